// Round 4
// baseline (189.405 us; speedup 1.0000x reference)
//
#include <hip/hip_runtime.h>
#include <math.h>

typedef __attribute__((ext_vector_type(8))) short short8;
typedef __attribute__((ext_vector_type(4))) float f32x4;

constexpr int NB = 16, NS = 512, NT = 4096, IND0 = 512;

__device__ __forceinline__ unsigned short f2bf(float f) {
    __bf16 h = (__bf16)f;
    return __builtin_bit_cast(unsigned short, h);
}
__device__ __forceinline__ float bf2f(unsigned short h) {
    return __uint_as_float(((unsigned)h) << 16);
}

template<int N> __device__ __forceinline__ void vwait() {
    asm volatile("s_waitcnt vmcnt(%0)" :: "n"(N) : "memory");
    __builtin_amdgcn_sched_barrier(0);
}
__device__ __forceinline__ void bar() {
    __builtin_amdgcn_sched_barrier(0);
    __builtin_amdgcn_s_barrier();
    __builtin_amdgcn_sched_barrier(0);
}
__device__ __forceinline__ void gload_lds16(const unsigned short* g, unsigned short* l) {
    __builtin_amdgcn_global_load_lds(
        (const __attribute__((address_space(1))) unsigned int*)g,
        (__attribute__((address_space(3))) unsigned int*)l, 16, 0, 0);
}

// ---------------------------------------------------------------------------
// Bulk f32 -> bf16 cast (emb -> emb_bf). n8 = elements/8.
__global__ void cast_bf16_kernel(const float* __restrict__ src,
                                 unsigned short* __restrict__ dst, int n8) {
    int i = blockIdx.x * blockDim.x + threadIdx.x;
    if (i >= n8) return;
    const float4* p = (const float4*)(src + (size_t)i * 8);
    float4 v0 = p[0], v1 = p[1];
    short8 o;
    o[0] = (short)f2bf(v0.x); o[1] = (short)f2bf(v0.y);
    o[2] = (short)f2bf(v0.z); o[3] = (short)f2bf(v0.w);
    o[4] = (short)f2bf(v1.x); o[5] = (short)f2bf(v1.y);
    o[6] = (short)f2bf(v1.z); o[7] = (short)f2bf(v1.w);
    *(short8*)(dst + (size_t)i * 8) = o;
}

// ---------------------------------------------------------------------------
// Weight prep: src (256, IND, 3) f32 -> bf16 fragments in exact MFMA B order.
template<int IND>
__global__ void wprep_kernel(const float* __restrict__ src,
                             unsigned short* __restrict__ dst) {
    constexpr int LOGIND = (IND == 512) ? 9 : 8;
    int total = 256 * 3 * IND;
    for (int idx = blockIdx.x * blockDim.x + threadIdx.x; idx < total;
         idx += gridDim.x * blockDim.x) {
        int e  = idx & 7;
        int l  = (idx >> 3) & 63;
        int s  = (idx >> 9) & 1;
        int nf = (idx >> 10) & 3;
        int w  = (idx >> 12) & 3;
        int st = idx >> 14;
        int k   = st * 64 + s * 32 + ((l >> 4) << 3) + e;
        int col = w * 64 + nf * 16 + (l & 15);
        int i   = k & (IND - 1);
        int ko  = k >> LOGIND;
        dst[idx] = f2bf(src[(col * IND + i) * 3 + ko]);
    }
}

// ---------------------------------------------------------------------------
// Per-batch cumsum + frame->phoneme index table; block 0 zeroes the zeropage.
__global__ void cumidx_kernel(const int* __restrict__ dur, int* __restrict__ idxarr,
                              unsigned short* __restrict__ zp) {
    __shared__ int cs[NS];
    __shared__ int wsum[4];
    int b = blockIdx.x, t = threadIdx.x, w = t >> 6, lane = t & 63;
    if (b == 0 && t < 8) zp[t] = 0;
    int v0 = dur[b * NS + t * 2], v1 = dur[b * NS + t * 2 + 1];
    int pair = v0 + v1;
    int incl = pair;
    for (int off = 1; off < 64; off <<= 1) {
        int n = __shfl_up(incl, off, 64);
        if (lane >= off) incl += n;
    }
    if (lane == 63) wsum[w] = incl;
    __syncthreads();
    int pre = 0;
    #pragma unroll
    for (int i = 0; i < 4; ++i) if (i < w) pre += wsum[i];
    incl += pre;
    cs[t * 2] = incl - v1;
    cs[t * 2 + 1] = incl;
    __syncthreads();
    int total = cs[NS - 1];
    for (int f = t; f < NT; f += 256) {
        int lo = 0, hi = NS;
        while (lo < hi) {
            int mid = (lo + hi) >> 1;
            if (cs[mid] <= f) lo = mid + 1; else hi = mid;
        }
        idxarr[b * NT + f] = (f < total) ? (lo < NS ? lo : NS - 1) : -1;
    }
}

// ---------------------------------------------------------------------------
// Fused conv1d(k=3,pad=1)+bias+relu+LayerNorm(256) [+1x1 head], bf16 MFMA.
// Block: BM x 256, 4 waves (wave tile BM x 64), BK=64.
// A: global_load_lds DMA, double-buffered, XOR-16B swizzle via pre-swizzled
//    per-lane source addresses; rowid table in LDS. Counted-vmcnt pipeline
//    with raw barriers (no vmcnt(0) drain in loop).
// B: direct per-lane fragment loads from pre-swizzled global (no LDS).
// FIN: 0 = bf16 hout; 1 = dur head exp/max1; 2 = f0 head.
template<int GATHER, int BM, int IND, int FIN, int LOGSL>
__global__ __launch_bounds__(256)
void conv_mfma(const unsigned short* __restrict__ src,
               const int* __restrict__ idxarr,
               const unsigned short* __restrict__ Bs,
               const unsigned short* __restrict__ zp,
               const float* __restrict__ bias, const float* __restrict__ gamma,
               const float* __restrict__ beta, unsigned short* __restrict__ hout,
               const float* __restrict__ wfin, const float* __restrict__ bfin,
               float* __restrict__ fout, float* __restrict__ up) {
    constexpr int K = 3 * IND;
    constexpr int NSTEP = K / 64;               // 24 or 12 (even)
    constexpr int KOSH = (IND == 512) ? 3 : 2;  // st -> ko shift
    constexpr int KOM = (IND / 64) - 1;
    constexpr int SL = 1 << LOGSL;
    constexpr int MF = BM / 16;
    constexpr int NISSUE = BM / 32;             // global_load_lds per thread/step
    constexpr int BUFS = BM * 64;               // ushorts per A buffer

    __shared__ unsigned short smem[2 * BUFS];
    __shared__ int rowid[BM + 2];

    const int t = threadIdx.x;
    const int m0 = blockIdx.x * BM;
    const int w = t >> 6, l = t & 63, llo = l & 15, lhi = l >> 4;

    // rowid[i]: global source row for block-row (i-1), or -1 (zero pad)
    {
        int as0 = m0 & (SL - 1);
        int ab = m0 >> LOGSL;
        for (int i = t; i < BM + 2; i += 256) {
            int tr = as0 + i - 1;
            int r = -1;
            if (tr >= 0 && tr < SL) {
                if (GATHER) {
                    int ix = idxarr[(ab << LOGSL) + tr];
                    if (ix >= 0) r = ab * NS + ix;
                } else {
                    r = ab * SL + tr;
                }
            }
            rowid[i] = r;
        }
    }
    __syncthreads();

    f32x4 acc[MF][4];
    #pragma unroll
    for (int i = 0; i < MF; ++i)
        #pragma unroll
        for (int j = 0; j < 4; ++j) acc[i][j] = (f32x4){0.f, 0.f, 0.f, 0.f};

    short8 b0[8], b1[8];

    auto stage = [&](int st, int buf) {
        int ko = st >> KOSH;
        int i0 = (st & KOM) << 6;
        #pragma unroll
        for (int j = 0; j < NISSUE; ++j) {
            int arow = (w * NISSUE + j) * 8 + (l >> 3);
            int rid = rowid[arow + ko];
            const unsigned short* g = (rid >= 0)
                ? src + (size_t)rid * IND + i0 + (((l & 7) ^ (arow & 7)) << 3)
                : zp;
            gload_lds16(g, &smem[buf + (w * NISSUE + j) * 512]);
        }
    };
    auto loadB = [&](int st, short8* b) {
        const unsigned short* base = Bs + ((size_t)(st * 4 + w) * 8) * 512 + l * 8;
        #pragma unroll
        for (int s = 0; s < 2; ++s)
            #pragma unroll
            for (int nf = 0; nf < 4; ++nf)
                b[s * 4 + nf] = *(const short8*)(base + (nf * 2 + s) * 512);
    };
    auto mfmaPhase = [&](int buf, short8* bc) {
        #pragma unroll
        for (int s = 0; s < 2; ++s)
            #pragma unroll
            for (int mf = 0; mf < MF; ++mf) {
                int row = mf * 16 + llo;
                short8 af = *(const short8*)&smem[buf + row * 64 +
                                                 ((((s << 2) | lhi) ^ (row & 7)) << 3)];
                #pragma unroll
                for (int nf = 0; nf < 4; ++nf)
                    acc[mf][nf] = __builtin_amdgcn_mfma_f32_16x16x32_bf16(
                        af, bc[s * 4 + nf], acc[mf][nf], 0, 0, 0);
            }
    };
    auto upwrite = [&](int st, int buf) {
        int i0 = (st & KOM) << 6;
        int row = t >> 1, c0 = (t & 1) * 4;
        size_t basep = (size_t)(m0 + row) * IND0 + i0;
        #pragma unroll
        for (int jc = 0; jc < 4; ++jc) {
            int c = c0 + jc;
            short8 v = *(const short8*)&smem[buf + row * 64 + ((c ^ (row & 7)) << 3)];
            f32x4 lo, hi;
            #pragma unroll
            for (int e = 0; e < 4; ++e) {
                lo[e] = bf2f((unsigned short)v[e]);
                hi[e] = bf2f((unsigned short)v[4 + e]);
            }
            *(f32x4*)(up + basep + c * 8) = lo;
            *(f32x4*)(up + basep + c * 8 + 4) = hi;
        }
    };

    // --- pipelined K loop: 2 raw barriers/step, counted vmcnt (never 0) ---
    stage(0, 0);
    loadB(0, b0);
    vwait<8>();
    bar();
    for (int st = 0; st < NSTEP; st += 2) {
        // even: compute st (buf0,b0); prefetch st+1 into buf1,b1
        stage(st + 1, BUFS);
        loadB(st + 1, b1);
        vwait<NISSUE + 8>();
        bar();
        mfmaPhase(0, b0);
        if (GATHER) { if ((st >> KOSH) == 1) upwrite(st, 0); }
        bar();
        // odd: compute st+1 (buf1,b1); prefetch st+2 into buf0,b0
        if (st + 2 < NSTEP) {
            stage(st + 2, 0);
            loadB(st + 2, b0);
            vwait<NISSUE + 8>();
        } else {
            vwait<0>();
        }
        bar();
        mfmaPhase(BUFS, b1);
        if (GATHER) { if (((st + 1) >> KOSH) == 1) upwrite(st + 1, BUFS); }
        bar();
    }
    __syncthreads();

    // --- epilogue: bias+relu (regs) + LN via cross-wave reduce + emit ---
    float* red  = (float*)&smem[0];   // [BM][4][2]
    float* red2 = red + BM * 8;       // [BM][4]
    float gv[4], bev[4], wv[4];
    #pragma unroll
    for (int nf = 0; nf < 4; ++nf) {
        int col = w * 64 + nf * 16 + llo;
        float bv = bias[col];
        gv[nf] = gamma[col]; bev[nf] = beta[col];
        if (FIN != 0) wv[nf] = wfin[col];
        #pragma unroll
        for (int mf = 0; mf < MF; ++mf)
            #pragma unroll
            for (int r = 0; r < 4; ++r) {
                float v = acc[mf][nf][r] + bv;
                acc[mf][nf][r] = v > 0.f ? v : 0.f;
            }
    }
    #pragma unroll
    for (int mf = 0; mf < MF; ++mf)
        #pragma unroll
        for (int r = 0; r < 4; ++r) {
            float s = 0.f, q = 0.f;
            #pragma unroll
            for (int nf = 0; nf < 4; ++nf) { float v = acc[mf][nf][r]; s += v; q += v * v; }
            #pragma unroll
            for (int off = 1; off < 16; off <<= 1) {
                s += __shfl_xor(s, off); q += __shfl_xor(q, off);
            }
            if (llo == 0) {
                int row = mf * 16 + lhi * 4 + r;
                red[row * 8 + w * 2] = s;
                red[row * 8 + w * 2 + 1] = q;
            }
        }
    __syncthreads();
    #pragma unroll
    for (int mf = 0; mf < MF; ++mf)
        #pragma unroll
        for (int r = 0; r < 4; ++r) {
            int row = mf * 16 + lhi * 4 + r;
            float s = red[row * 8 + 0] + red[row * 8 + 2] + red[row * 8 + 4] + red[row * 8 + 6];
            float q = red[row * 8 + 1] + red[row * 8 + 3] + red[row * 8 + 5] + red[row * 8 + 7];
            float mean = s * (1.f / 256.f);
            float rs = rsqrtf(q * (1.f / 256.f) - mean * mean + 1e-5f);
            if (FIN == 0) {
                #pragma unroll
                for (int nf = 0; nf < 4; ++nf) {
                    int col = w * 64 + nf * 16 + llo;
                    hout[(size_t)(m0 + row) * 256 + col] =
                        f2bf((acc[mf][nf][r] - mean) * rs * gv[nf] + bev[nf]);
                }
            } else {
                float pd = 0.f;
                #pragma unroll
                for (int nf = 0; nf < 4; ++nf)
                    pd += ((acc[mf][nf][r] - mean) * rs * gv[nf] + bev[nf]) * wv[nf];
                #pragma unroll
                for (int off = 1; off < 16; off <<= 1) pd += __shfl_xor(pd, off);
                if (llo == 0) red2[row * 4 + w] = pd;
            }
        }
    if (FIN != 0) {
        __syncthreads();
        if (t < BM) {
            float rsum = red2[t * 4] + red2[t * 4 + 1] + red2[t * 4 + 2] + red2[t * 4 + 3]
                       + bfin[0];
            if (FIN == 1) { rsum = expf(rsum); rsum = rsum > 1.f ? rsum : 1.f; }
            fout[m0 + t] = rsum;
        }
    }
}

// ---------------------------------------------------------------------------
extern "C" void kernel_launch(void* const* d_in, const int* in_sizes, int n_in,
                              void* d_out, int out_size, void* d_ws, size_t ws_size,
                              hipStream_t stream) {
    const float* emb    = (const float*)d_in[0];
    const int*   dur    = (const int*)  d_in[1];
    const float* dp_w1  = (const float*)d_in[2];
    const float* dp_b1  = (const float*)d_in[3];
    const float* dp_g1  = (const float*)d_in[4];
    const float* dp_be1 = (const float*)d_in[5];
    const float* dp_w2  = (const float*)d_in[6];
    const float* dp_b2  = (const float*)d_in[7];
    const float* dp_g2  = (const float*)d_in[8];
    const float* dp_be2 = (const float*)d_in[9];
    const float* dp_w3  = (const float*)d_in[10];
    const float* dp_b3  = (const float*)d_in[11];
    const float* f0_w1  = (const float*)d_in[12];
    const float* f0_b1  = (const float*)d_in[13];
    const float* f0_g1  = (const float*)d_in[14];
    const float* f0_be1 = (const float*)d_in[15];
    const float* f0_w2  = (const float*)d_in[16];
    const float* f0_b2  = (const float*)d_in[17];

    float* up   = (float*)d_out;                       // (16, 4096, 512)
    float* pdur = up + (size_t)NB * NT * IND0;         // (16, 512)
    float* pf0  = pdur + NB * NS;                      // (16, 4096)

    char* ws = (char*)d_ws;
    int*            idxarr = (int*)(ws);                          // 256 KB
    unsigned short* zp     = (unsigned short*)(ws + 262144);      // 512 B
    unsigned short* Bs1    = (unsigned short*)(ws + 262656);      // 768 KB
    unsigned short* Bs2    = (unsigned short*)(ws + 1049088);     // 384 KB
    unsigned short* Bsf    = (unsigned short*)(ws + 1442304);     // 768 KB
    unsigned short* h1     = (unsigned short*)(ws + 2228736);     // 4 MB
    unsigned short* emb_bf = (unsigned short*)(ws + 6423040);     // 8 MB

    cumidx_kernel<<<NB, 256, 0, stream>>>(dur, idxarr, zp);
    cast_bf16_kernel<<<2048, 256, 0, stream>>>(emb, emb_bf, NB * NS * IND0 / 8);
    wprep_kernel<512><<<768, 256, 0, stream>>>(dp_w1, Bs1);
    wprep_kernel<256><<<384, 256, 0, stream>>>(dp_w2, Bs2);
    wprep_kernel<512><<<768, 256, 0, stream>>>(f0_w1, Bsf);

    // duration predictor conv1: emb_bf -> h1 (bf16)
    conv_mfma<0, 32, 512, 0, 9><<<NB * NS / 32, 256, 0, stream>>>(
        emb_bf, nullptr, Bs1, zp, dp_b1, dp_g1, dp_be1, h1, nullptr, nullptr,
        nullptr, nullptr);
    // duration predictor conv2 + dur head: h1 -> pdur
    conv_mfma<0, 32, 256, 1, 9><<<NB * NS / 32, 256, 0, stream>>>(
        h1, nullptr, Bs2, zp, dp_b2, dp_g2, dp_be2, nullptr, dp_w3, dp_b3,
        pdur, nullptr);
    // f0 conv + head: gather emb_bf rows via idxarr -> pf0, fused `up` write
    conv_mfma<1, 128, 512, 2, 12><<<NB * NT / 128, 256, 0, stream>>>(
        emb_bf, idxarr, Bsf, zp, f0_b1, f0_g1, f0_be1, nullptr, f0_w2, f0_b2,
        pf0, up);
}

// Round 5
// 150.820 us; speedup vs baseline: 1.2558x; 1.2558x over previous
//
#include <hip/hip_runtime.h>
#include <math.h>

typedef __attribute__((ext_vector_type(8))) short short8;
typedef __attribute__((ext_vector_type(4))) float f32x4;
typedef __attribute__((ext_vector_type(4))) unsigned short us4;

constexpr int NB = 16, NS = 512, NT = 4096, IND0 = 512;

__device__ __forceinline__ unsigned short f2bf(float f) {
    __bf16 h = (__bf16)f;
    return __builtin_bit_cast(unsigned short, h);
}
__device__ __forceinline__ float bf2f(unsigned short h) {
    return __uint_as_float(((unsigned)h) << 16);
}

// ---------------------------------------------------------------------------
// Merged prep kernel, dispatched by block range:
//  [0,16)      : per-batch cumsum + frame->phoneme idx table (+ zp zero)
//  [16,2064)   : emb f32 -> bf16 cast
//  [2064,3600) : wprep dp_w1 -> Bs1   (IND=512)
//  [3600,4368) : wprep dp_w2 -> Bs2   (IND=256)
//  [4368,5904) : wprep f0_w1 -> Bsf   (IND=512)
__device__ __forceinline__ void wprep_one(const float* __restrict__ src,
                                          unsigned short* __restrict__ dst,
                                          int idx, int LOGIND) {
    int IND = 1 << LOGIND;
    int e  = idx & 7;
    int l  = (idx >> 3) & 63;
    int s  = (idx >> 9) & 1;
    int nf = (idx >> 10) & 3;
    int w  = (idx >> 12) & 3;
    int st = idx >> 14;
    int k   = st * 64 + s * 32 + ((l >> 4) << 3) + e;
    int col = w * 64 + nf * 16 + (l & 15);
    int i   = k & (IND - 1);
    int ko  = k >> LOGIND;
    dst[idx] = f2bf(src[(col * IND + i) * 3 + ko]);
}

__global__ __launch_bounds__(256)
void prep_kernel(const float* __restrict__ emb, const int* __restrict__ dur,
                 const float* __restrict__ dp_w1, const float* __restrict__ dp_w2,
                 const float* __restrict__ f0_w1,
                 unsigned short* __restrict__ emb_bf, int* __restrict__ idxarr,
                 unsigned short* __restrict__ zp,
                 unsigned short* __restrict__ Bs1, unsigned short* __restrict__ Bs2,
                 unsigned short* __restrict__ Bsf) {
    __shared__ int cs[NS];
    __shared__ int wsum[4];
    const int bid = blockIdx.x, t = threadIdx.x;
    if (bid < 16) {
        // --- cumsum + idx table ---
        int b = bid, w = t >> 6, lane = t & 63;
        if (b == 0 && t < 8) zp[t] = 0;
        int v0 = dur[b * NS + t * 2], v1 = dur[b * NS + t * 2 + 1];
        int incl = v0 + v1;
        for (int off = 1; off < 64; off <<= 1) {
            int n = __shfl_up(incl, off, 64);
            if (lane >= off) incl += n;
        }
        if (lane == 63) wsum[w] = incl;
        __syncthreads();
        int pre = 0;
        #pragma unroll
        for (int i = 0; i < 4; ++i) if (i < w) pre += wsum[i];
        incl += pre;
        cs[t * 2] = incl - v1;
        cs[t * 2 + 1] = incl;
        __syncthreads();
        int total = cs[NS - 1];
        for (int f = t; f < NT; f += 256) {
            int lo = 0, hi = NS;
            while (lo < hi) {
                int mid = (lo + hi) >> 1;
                if (cs[mid] <= f) lo = mid + 1; else hi = mid;
            }
            idxarr[b * NT + f] = (f < total) ? (lo < NS ? lo : NS - 1) : -1;
        }
    } else if (bid < 2064) {
        int i = (bid - 16) * 256 + t;   // short8 index; total 524288
        const float4* p = (const float4*)(emb + (size_t)i * 8);
        float4 v0 = p[0], v1 = p[1];
        short8 o;
        o[0] = (short)f2bf(v0.x); o[1] = (short)f2bf(v0.y);
        o[2] = (short)f2bf(v0.z); o[3] = (short)f2bf(v0.w);
        o[4] = (short)f2bf(v1.x); o[5] = (short)f2bf(v1.y);
        o[6] = (short)f2bf(v1.z); o[7] = (short)f2bf(v1.w);
        *(short8*)(emb_bf + (size_t)i * 8) = o;
    } else if (bid < 3600) {
        wprep_one(dp_w1, Bs1, (bid - 2064) * 256 + t, 9);
    } else if (bid < 4368) {
        wprep_one(dp_w2, Bs2, (bid - 3600) * 256 + t, 8);
    } else {
        wprep_one(f0_w1, Bsf, (bid - 4368) * 256 + t, 9);
    }
}

// ---------------------------------------------------------------------------
// Fused conv1d(k=3,pad=1)+bias+relu+LayerNorm(256) [+1x1 head], bf16 MFMA.
// Block: BM x 256, 4 waves (wave tile BM x 64), BK=64, A LDS double-buffer
// (XOR-16B swizzle), B single register buffer loaded straight from
// pre-swizzled global (no LDS). Per-thread rid[3] hoists all row-index /
// gather lookups out of the K loop. One __syncthreads per K step.
// GATHER=1: rows via idxarr + fused f32 `up` write during ko==1 steps.
// FIN: 0 = bf16 hout; 1 = dur head exp/max1; 2 = f0 head.
template<int GATHER, int BM, int IND, int FIN, int LOGSL>
__global__ __launch_bounds__(256, 3)
void conv_mfma(const unsigned short* __restrict__ src,
               const int* __restrict__ idxarr,
               const unsigned short* __restrict__ Bs,
               const float* __restrict__ bias, const float* __restrict__ gamma,
               const float* __restrict__ beta, unsigned short* __restrict__ hout,
               const float* __restrict__ wfin, const float* __restrict__ bfin,
               float* __restrict__ fout, float* __restrict__ up) {
    constexpr int K = 3 * IND;
    constexpr int NSTEP = K / 64;               // 24 or 12
    constexpr int KOSH = (IND == 512) ? 3 : 2;  // st -> ko shift
    constexpr int KOM = (IND / 64) - 1;
    constexpr int SL = 1 << LOGSL;
    constexpr int TPR = 256 / BM;               // threads per staged row
    constexpr int CH  = 8 / TPR;                // 16B chunks per thread
    constexpr int MF  = BM / 16;
    constexpr int BUFS = BM * 64;               // ushorts per A buffer

    __shared__ unsigned short smem[BM * 256];   // union: 2 A-bufs | H tile

    const int t = threadIdx.x;
    const int m0 = blockIdx.x * BM;
    const int w = t >> 6, l = t & 63, llo = l & 15, lhi = l >> 4;

    const int arow = t / TPR, sub = t % TPR;
    const int am = m0 + arow, ab = am >> LOGSL, as_ = am & (SL - 1);

    // Hoisted per-tap source rows (or -1 = zero pad)
    int rid[3];
    #pragma unroll
    for (int ko = 0; ko < 3; ++ko) {
        int tr = as_ + ko - 1;
        int r = -1;
        if (tr >= 0 && tr < SL) {
            if (GATHER) {
                int ix = idxarr[(ab << LOGSL) + tr];
                if (ix >= 0) r = ab * NS + ix;
            } else {
                r = ab * SL + tr;
            }
        }
        rid[ko] = r;
    }

    f32x4 acc[MF][4];
    #pragma unroll
    for (int i = 0; i < MF; ++i)
        #pragma unroll
        for (int j = 0; j < 4; ++j) acc[i][j] = (f32x4){0.f, 0.f, 0.f, 0.f};

    short8 a[CH];
    short8 b[8];

    auto stageA = [&](int st) {
        int ko = st >> KOSH;
        int i0 = (st & KOM) << 6;
        int r = rid[ko];
        if (r >= 0) {
            const unsigned short* p = src + (size_t)r * IND + i0 + sub * CH * 8;
            #pragma unroll
            for (int j = 0; j < CH; ++j) a[j] = *(const short8*)(p + j * 8);
        } else {
            #pragma unroll
            for (int j = 0; j < CH; ++j) a[j] = short8{0,0,0,0,0,0,0,0};
        }
    };
    auto dsWriteA = [&](int st) {
        int buf = (st & 1) * BUFS;
        #pragma unroll
        for (int j = 0; j < CH; ++j)
            *(short8*)&smem[buf + arow * 64 + (((sub * CH + j) ^ (arow & 7)) << 3)] = a[j];
        if (GATHER && (st >> KOSH) == 1) {  // staged rows == `up` rows
            int i0 = (st & KOM) << 6;
            float* dstp = up + (size_t)am * IND0 + i0 + sub * CH * 8;
            #pragma unroll
            for (int j = 0; j < CH; ++j) {
                f32x4 lo, hi;
                #pragma unroll
                for (int e = 0; e < 4; ++e) {
                    lo[e] = bf2f((unsigned short)a[j][e]);
                    hi[e] = bf2f((unsigned short)a[j][4 + e]);
                }
                *(f32x4*)(dstp + j * 8) = lo;
                *(f32x4*)(dstp + j * 8 + 4) = hi;
            }
        }
    };
    auto loadB = [&](int st) {
        const unsigned short* base = Bs + ((size_t)(st * 4 + w) * 8) * 512 + l * 8;
        #pragma unroll
        for (int s = 0; s < 2; ++s)
            #pragma unroll
            for (int nf = 0; nf < 4; ++nf)
                b[s * 4 + nf] = *(const short8*)(base + (nf * 2 + s) * 512);
    };
    auto mfmaPhase = [&](int buf) {
        #pragma unroll
        for (int s = 0; s < 2; ++s)
            #pragma unroll
            for (int mf = 0; mf < MF; ++mf) {
                int row = mf * 16 + llo;
                short8 af = *(const short8*)&smem[buf + row * 64 +
                                                 ((((s << 2) | lhi) ^ (row & 7)) << 3)];
                #pragma unroll
                for (int nf = 0; nf < 4; ++nf)
                    acc[mf][nf] = __builtin_amdgcn_mfma_f32_16x16x32_bf16(
                        af, b[s * 4 + nf], acc[mf][nf], 0, 0, 0);
            }
    };

    // --- K loop: A dbuf with 1 barrier/step, B single reg buffer ---
    stageA(0);
    dsWriteA(0);
    stageA(1);
    __syncthreads();
    for (int st = 0; st < NSTEP; ++st) {
        loadB(st);
        if (st + 1 < NSTEP) dsWriteA(st + 1);
        if (st + 2 < NSTEP) stageA(st + 2);
        mfmaPhase((st & 1) * BUFS);
        __syncthreads();
    }

    // --- epilogue: bias+relu -> H tile (XOR-swizzled), LN, emit ---
    unsigned short* H = smem;
    #pragma unroll
    for (int nf = 0; nf < 4; ++nf) {
        int col = w * 64 + nf * 16 + llo;
        float bv = bias[col];
        #pragma unroll
        for (int mf = 0; mf < MF; ++mf)
            #pragma unroll
            for (int r = 0; r < 4; ++r) {
                int row = mf * 16 + lhi * 4 + r;
                float v = acc[mf][nf][r] + bv;
                v = v > 0.f ? v : 0.f;
                H[row * 256 + ((((col >> 2) ^ (row & 15)) << 2) | (col & 3))] = f2bf(v);
            }
    }
    __syncthreads();

    constexpr int Q = 256 / BM;   // threads per row
    constexpr int NG = 64 / Q;    // 4-col groups per thread
    int row = t / Q, jj = t % Q;
    const unsigned short* Hr = H + row * 256;
    int rx = row & 15;
    float sum = 0.f, sq = 0.f;
    #pragma unroll
    for (int c4 = 0; c4 < NG; ++c4) {
        int g = jj * NG + c4;
        us4 hv = *(const us4*)&Hr[(g ^ rx) << 2];
        #pragma unroll
        for (int e = 0; e < 4; ++e) { float f = bf2f(hv[e]); sum += f; sq += f * f; }
    }
    #pragma unroll
    for (int off = Q / 2; off >= 1; off >>= 1) {
        sum += __shfl_xor(sum, off);
        sq  += __shfl_xor(sq, off);
    }
    float mean = sum * (1.f / 256.f);
    float var  = sq * (1.f / 256.f) - mean * mean;
    float rs   = rsqrtf(var + 1e-5f);
    int m = m0 + row;

    if (FIN == 0) {
        #pragma unroll
        for (int c4 = 0; c4 < NG; ++c4) {
            int g = jj * NG + c4;
            us4 hv = *(const us4*)&Hr[(g ^ rx) << 2];
            float4 gv = *(const float4*)&gamma[g * 4];
            float4 bv = *(const float4*)&beta[g * 4];
            us4 ov;
            ov[0] = f2bf((bf2f(hv[0]) - mean) * rs * gv.x + bv.x);
            ov[1] = f2bf((bf2f(hv[1]) - mean) * rs * gv.y + bv.y);
            ov[2] = f2bf((bf2f(hv[2]) - mean) * rs * gv.z + bv.z);
            ov[3] = f2bf((bf2f(hv[3]) - mean) * rs * gv.w + bv.w);
            *(us4*)&hout[(size_t)m * 256 + g * 4] = ov;
        }
    } else {
        float part = 0.f;
        #pragma unroll
        for (int c4 = 0; c4 < NG; ++c4) {
            int g = jj * NG + c4;
            us4 hv = *(const us4*)&Hr[(g ^ rx) << 2];
            float4 gv = *(const float4*)&gamma[g * 4];
            float4 bv = *(const float4*)&beta[g * 4];
            float4 wv = *(const float4*)&wfin[g * 4];
            part += ((bf2f(hv[0]) - mean) * rs * gv.x + bv.x) * wv.x;
            part += ((bf2f(hv[1]) - mean) * rs * gv.y + bv.y) * wv.y;
            part += ((bf2f(hv[2]) - mean) * rs * gv.z + bv.z) * wv.z;
            part += ((bf2f(hv[3]) - mean) * rs * gv.w + bv.w) * wv.w;
        }
        #pragma unroll
        for (int off = Q / 2; off >= 1; off >>= 1) part += __shfl_xor(part, off);
        if (jj == 0) {
            float r = part + bfin[0];
            if (FIN == 1) { r = expf(r); r = r > 1.f ? r : 1.f; }
            fout[m] = r;
        }
    }
}

// ---------------------------------------------------------------------------
extern "C" void kernel_launch(void* const* d_in, const int* in_sizes, int n_in,
                              void* d_out, int out_size, void* d_ws, size_t ws_size,
                              hipStream_t stream) {
    const float* emb    = (const float*)d_in[0];
    const int*   dur    = (const int*)  d_in[1];
    const float* dp_w1  = (const float*)d_in[2];
    const float* dp_b1  = (const float*)d_in[3];
    const float* dp_g1  = (const float*)d_in[4];
    const float* dp_be1 = (const float*)d_in[5];
    const float* dp_w2  = (const float*)d_in[6];
    const float* dp_b2  = (const float*)d_in[7];
    const float* dp_g2  = (const float*)d_in[8];
    const float* dp_be2 = (const float*)d_in[9];
    const float* dp_w3  = (const float*)d_in[10];
    const float* dp_b3  = (const float*)d_in[11];
    const float* f0_w1  = (const float*)d_in[12];
    const float* f0_b1  = (const float*)d_in[13];
    const float* f0_g1  = (const float*)d_in[14];
    const float* f0_be1 = (const float*)d_in[15];
    const float* f0_w2  = (const float*)d_in[16];
    const float* f0_b2  = (const float*)d_in[17];

    float* up   = (float*)d_out;                       // (16, 4096, 512)
    float* pdur = up + (size_t)NB * NT * IND0;         // (16, 512)
    float* pf0  = pdur + NB * NS;                      // (16, 4096)

    char* ws = (char*)d_ws;
    int*            idxarr = (int*)(ws);                          // 256 KB
    unsigned short* zp     = (unsigned short*)(ws + 262144);      // 512 B
    unsigned short* Bs1    = (unsigned short*)(ws + 262656);      // 768 KB
    unsigned short* Bs2    = (unsigned short*)(ws + 1049088);     // 384 KB
    unsigned short* Bsf    = (unsigned short*)(ws + 1442304);     // 768 KB
    unsigned short* h1     = (unsigned short*)(ws + 2228736);     // 4 MB
    unsigned short* emb_bf = (unsigned short*)(ws + 6423040);     // 8 MB

    prep_kernel<<<5904, 256, 0, stream>>>(emb, dur, dp_w1, dp_w2, f0_w1,
                                          emb_bf, idxarr, zp, Bs1, Bs2, Bsf);

    // duration predictor conv1: emb_bf -> h1 (bf16)
    conv_mfma<0, 32, 512, 0, 9><<<NB * NS / 32, 256, 0, stream>>>(
        emb_bf, nullptr, Bs1, dp_b1, dp_g1, dp_be1, h1, nullptr, nullptr,
        nullptr, nullptr);
    // duration predictor conv2 + dur head: h1 -> pdur
    conv_mfma<0, 32, 256, 1, 9><<<NB * NS / 32, 256, 0, stream>>>(
        h1, nullptr, Bs2, dp_b2, dp_g2, dp_be2, nullptr, dp_w3, dp_b3,
        pdur, nullptr);
    // f0 conv + head: gather emb_bf rows via idxarr -> pf0, fused `up` write
    conv_mfma<1, 64, 512, 2, 12><<<NB * NT / 64, 256, 0, stream>>>(
        emb_bf, idxarr, Bsf, f0_b1, f0_g1, f0_be1, nullptr, f0_w2, f0_b2,
        pf0, up);
}